// Round 4
// baseline (370.274 us; speedup 1.0000x reference)
//
#include <hip/hip_runtime.h>
#include <stdint.h>

// B=32, D=64, H=64, W=64, K=512; N = B*H*W = 131072 tokens.
#define K_CODES 512
#define N_TOK   131072
#define ZQ_ELEMS 8388608   // 32*64*64*64
#define CAP 46             // per-lane candidate capacity
#define CSTRIDE 47         // LDS row stride (47 mod 32 = 15, coprime -> conflict-free)
#define ECSTRIDE 65        // codebook LDS row stride in floats (65 mod 32 = 1)

__device__ __forceinline__ uint32_t rotl32(uint32_t x, int d) {
  return (x << d) | (x >> (32 - d));
}

// JAX threefry2x32, key=(0,42), partitionable path: bits = out0^out1, counter=(0,lo).
__device__ __forceinline__ uint32_t tf_bits_xor(uint32_t lo) {
  const uint32_t ks0 = 0u, ks1 = 42u, ks2 = 0x1BD11BDAu ^ 0u ^ 42u;
  uint32_t x0 = 0u;        // hi(=0) + ks0
  uint32_t x1 = lo + ks1;
#define TFR(r) { x0 += x1; x1 = rotl32(x1, (r)); x1 ^= x0; }
  TFR(13) TFR(15) TFR(26) TFR(6)
  x0 += ks1; x1 += ks2 + 1u;
  TFR(17) TFR(29) TFR(16) TFR(24)
  x0 += ks2; x1 += ks0 + 2u;
  TFR(13) TFR(15) TFR(26) TFR(6)
  x0 += ks0; x1 += ks1 + 3u;
  TFR(17) TFR(29) TFR(16) TFR(24)
  x0 += ks1; x1 += ks2 + 4u;
  TFR(13) TFR(15) TFR(26) TFR(6)
  x0 += ks2; x1 += ks0 + 5u;
#undef TFR
  return x0 ^ x1;
}

// EXACT float sequence of the round-2 pass (monotone nondecreasing in u23).
__device__ __forceinline__ float g_of_u23(uint32_t u23) {
  float u0 = (float)u23 * 0x1p-23f;
  float u  = fmaxf(u0 + 1.17549435e-38f, 1.17549435e-38f);
  float nl = -logf(u);
  return -logf(nl);
}

// Conservative packed threshold: any code with exact g < (gthr - margins) is pruned.
// -16 u23-units ~ 5e-5 in g near the top; float slop ~1e-6. Plus caller's 0.001.
__device__ __forceinline__ uint32_t thr_from_gthr(float gthr) {
  float u_t = expf(-expf(-gthr));
  int B = (int)floorf(u_t * 8388608.0f) - 16;
  if (B < 0) B = 0;
  return ((uint32_t)B) << 9;
}

// Exact v — identical arithmetic for LDS and global e (4 chains, pairwise sum,
// fmaf(kappa,s,g) == compiler-contracted round-2 "g + kappa*s").
__device__ __forceinline__ float eval_e(uint32_t p, const float* z, const float* e,
                                        float kappa, float* s_out) {
  float s0 = 0.f, s1 = 0.f, s2 = 0.f, s3 = 0.f;
#pragma unroll
  for (int d = 0; d < 64; d += 4) {
    s0 = fmaf(z[d + 0], e[d + 0], s0);
    s1 = fmaf(z[d + 1], e[d + 1], s1);
    s2 = fmaf(z[d + 2], e[d + 2], s2);
    s3 = fmaf(z[d + 3], e[d + 3], s3);
  }
  float s = (s0 + s1) + (s2 + s3);
  *s_out = s;
  float g = g_of_u23(p >> 9);
  return fmaf(kappa, s, g);
}

// ---------------- kernel 0: row-normalize codebook ----------------
__global__ void k_norm(const float* __restrict__ w, float* __restrict__ embn) {
  int k = blockIdx.x;   // 512 rows
  int d = threadIdx.x;  // 64 lanes
  float v = w[(k << 6) + d];
  float s = v * v;
#pragma unroll
  for (int off = 1; off < 64; off <<= 1) s += __shfl_xor(s, off);
  embn[(k << 6) + d] = v / sqrtf(s);
}

// ---------------- kernel 1: RNG-filtered gumbel argmax ----------------
__global__ __launch_bounds__(256, 2) void k_top(
    const float* __restrict__ z_e, const float* __restrict__ embn,
    const float* __restrict__ kappa_p, int* __restrict__ idx_ws,
    float* __restrict__ partials, float* __restrict__ out_idx) {
  __shared__ uint32_t cand[256 * CSTRIDE];     // 48128 B
  __shared__ float ecache[64 * ECSTRIDE];      // 16640 B
  __shared__ float redbuf[4];

  const float kappa = kappa_p[0];
  const int tid = threadIdx.x;
  const int t = blockIdx.x * 256 + tid;
  const int b = t >> 12, rem = t & 4095, h = rem >> 6, w = rem & 63;
  const float* zp = z_e + (b << 18) + (h << 6) + w;   // stride 4096 floats in d

  float z[64];
#pragma unroll
  for (int d = 0; d < 64; ++d) z[d] = zp[d << 12];

  const uint32_t base = (uint32_t)t << 9;   // t * 512

  // ---- Phase A: RNG-only over k<128, track bits-max ----
  uint32_t rmA = 0;
  for (int kb = 0; kb < 128; kb += 4) {
#pragma unroll
    for (int j = 0; j < 4; ++j) {
      uint32_t bits = tf_bits_xor(base + (uint32_t)(kb + j));
      uint32_t p = (bits & 0xFFFFFE00u) | (uint32_t)(kb + j);
      rmA = rmA > p ? rmA : p;
    }
  }
  float sA;
  float vA = eval_e(rmA, z, embn + ((rmA & 511u) << 6), kappa, &sA);
  // winner w: v_w >= vA  =>  g_w >= vA - kappa*s_w >= vA - kappa (s<=1+slop)
  uint32_t B0 = thr_from_gthr(vA - 1.0001f * kappa - 0.001f);

  // ---- Main RNG pass: append packed >= B0; record first lost k on overflow ----
  uint32_t rmM = rmA;
  int cnt = 0, kovf = 512;
  for (int kb = 0; kb < K_CODES; kb += 4) {
#pragma unroll
    for (int j = 0; j < 4; ++j) {
      int k = kb + j;
      uint32_t bits = tf_bits_xor(base + (uint32_t)k);
      uint32_t p = (bits & 0xFFFFFE00u) | (uint32_t)k;
      rmM = rmM > p ? rmM : p;
      if (p >= B0) {
        if (cnt < CAP) cand[tid * CSTRIDE + cnt] = p;
        else if (kovf == 512) kovf = k;   // all losses have k >= kovf
        ++cnt;
      }
    }
  }

  // ---- Tighten threshold from the global bits-max, prune list in place ----
  float vM = vA;
  if (rmM != rmA) { float sM; vM = eval_e(rmM, z, embn + ((rmM & 511u) << 6), kappa, &sM); }
  float Lb = fmaxf(vA, vM);
  uint32_t B2 = thr_from_gthr(Lb - 1.0001f * kappa - 0.001f);

  int cl0 = cnt < CAP ? cnt : CAP;
  int cl = 0;
  for (int j = 0; j < cl0; ++j) {
    uint32_t p = cand[tid * CSTRIDE + j];
    if (p >= B2) cand[tid * CSTRIDE + (cl++)] = p;   // preserves ascending k
  }

  // ---- Chunked LDS evaluation (8 chunks x 64 rows), ascending k, strict > ----
  float best = -INFINITY, bsim = 0.f;
  int bk = 0, jp = 0;
  for (int c = 0; c < 8; ++c) {
    __syncthreads();                                   // prev chunk fully consumed
    const float4* src = reinterpret_cast<const float4*>(embn + (c << 12));
#pragma unroll
    for (int i = 0; i < 4; ++i) {
      float4 v4 = src[(i << 8) + tid];                 // coalesced
      int fi = ((i << 8) + tid) << 2;                  // float index in chunk
      int row = fi >> 6, col = fi & 63;
      float* dst = ecache + row * ECSTRIDE + col;
      dst[0] = v4.x; dst[1] = v4.y; dst[2] = v4.z; dst[3] = v4.w;
    }
    __syncthreads();
    int kend = (c + 1) << 6;
    while (jp < cl) {
      uint32_t p = cand[tid * CSTRIDE + jp];
      int k = (int)(p & 511u);
      if (k >= kend) break;
      ++jp;
      float s;
      float v = eval_e(p, z, ecache + (k - (c << 6)) * ECSTRIDE, kappa, &s);
      if (v > best) { best = v; bk = k; bsim = s; }
    }
  }

  // ---- Exact fallback for overflowed lanes: rescan k in [kovf, 512) ----
  if (cnt > CAP) {
    for (int k = kovf; k < K_CODES; ++k) {
      uint32_t bits = tf_bits_xor(base + (uint32_t)k);
      uint32_t p = (bits & 0xFFFFFE00u) | (uint32_t)k;
      if (p >= B2) {
        float s;
        float v = eval_e(p, z, embn + (k << 6), kappa, &s);
        if (v > best) { best = v; bk = k; bsim = s; }
      }
    }
  }

  idx_ws[t] = bk;
  out_idx[t] = (float)bk;

  // deterministic block reduction of kappa*(1 - chosen_sim)
  float r = kappa * (1.0f - bsim);
#pragma unroll
  for (int off = 32; off; off >>= 1) r += __shfl_down(r, off);
  int lane = tid & 63, wid = tid >> 6;
  if (lane == 0) redbuf[wid] = r;
  __syncthreads();
  if (tid == 0) partials[blockIdx.x] = (redbuf[0] + redbuf[1]) + (redbuf[2] + redbuf[3]);
}

// ---------------- kernel 2: reduce partials -> reg ----------------
__global__ void k_reg(const float* __restrict__ partials,
                      float* __restrict__ out_reg) {
  int lane = threadIdx.x;  // 64
  float s = 0.f;
#pragma unroll
  for (int j = 0; j < 8; ++j) s += partials[lane + (j << 6)];
#pragma unroll
  for (int off = 1; off < 64; off <<= 1) s += __shfl_xor(s, off);
  if (lane == 0) out_reg[0] = s * (1.0f / 131072.0f);
}

// ---------------- kernel 3: gather z_q via LDS transpose ----------------
// block = one (b,h): 64 tokens; stage their 64 codebook rows coalesced,
// emit out[b,d,h,w] with coalesced writes.
__global__ __launch_bounds__(256) void k_gather(
    const float* __restrict__ embn, const int* __restrict__ idx_ws,
    float* __restrict__ out_zq) {
  __shared__ float erow[64 * ECSTRIDE];
  __shared__ int sidx[64];
  int blk = blockIdx.x;            // 2048 = 32*64
  int b = blk >> 6, h = blk & 63;
  int tid = threadIdx.x;
  int lane = tid & 63, wid = tid >> 6;

  if (tid < 64) sidx[tid] = idx_ws[(b << 12) + (h << 6) + tid];
  __syncthreads();
  for (int r = wid; r < 64; r += 4)            // wave per row: 4 lines/load
    erow[r * ECSTRIDE + lane] = embn[(sidx[r] << 6) + lane];
  __syncthreads();

  int w = tid & 63;
  int d0 = tid >> 6;               // 0..3
  float* outp = out_zq + (b << 18) + (h << 6) + w;
#pragma unroll
  for (int i = 0; i < 16; ++i) {
    int d = (i << 2) + d0;
    outp[d << 12] = erow[w * ECSTRIDE + d];    // (w+d)%32 banks: conflict-free
  }
}

extern "C" void kernel_launch(void* const* d_in, const int* in_sizes, int n_in,
                              void* d_out, int out_size, void* d_ws, size_t ws_size,
                              hipStream_t stream) {
  const float* z_e    = (const float*)d_in[0];
  const float* emb_w  = (const float*)d_in[1];
  const float* kappa  = (const float*)d_in[2];

  float* embn     = (float*)d_ws;                              // 32768 f32
  int*   idx_ws   = (int*)((char*)d_ws + 131072);              // 131072 i32
  float* partials = (float*)((char*)d_ws + 131072 + 524288);   // 512 f32

  float* out     = (float*)d_out;
  float* out_zq  = out;                    // [8388608]
  float* out_reg = out + ZQ_ELEMS;         // [1]
  float* out_idx = out + ZQ_ELEMS + 1;     // [131072]

  k_norm  <<<K_CODES, 64, 0, stream>>>(emb_w, embn);
  k_top   <<<N_TOK / 256, 256, 0, stream>>>(z_e, embn, kappa, idx_ws, partials, out_idx);
  k_reg   <<<1, 64, 0, stream>>>(partials, out_reg);
  k_gather<<<2048, 256, 0, stream>>>(embn, idx_ws, out_zq);
}

// Round 5
// 263.640 us; speedup vs baseline: 1.4045x; 1.4045x over previous
//
#include <hip/hip_runtime.h>
#include <stdint.h>

// B=32, D=64, H=64, W=64, K=512; N = B*H*W = 131072 tokens.
#define K_CODES 512
#define N_TOK   131072
#define ZQ_ELEMS 8388608   // 32*64*64*64
#define ZS_STRIDE 68       // floats: %4==0 (float4-aligned), %32==4 (bank spread)
#define ECSTRIDE 65        // k_gather LDS stride

__device__ __forceinline__ uint32_t rotl32(uint32_t x, int d) {
  return (x << d) | (x >> (32 - d));
}

// JAX threefry2x32, key=(0,42), partitionable path: bits = out0^out1, counter=(0,lo).
__device__ __forceinline__ uint32_t tf_bits_xor(uint32_t lo) {
  const uint32_t ks0 = 0u, ks1 = 42u, ks2 = 0x1BD11BDAu ^ 0u ^ 42u;
  uint32_t x0 = 0u;        // hi(=0) + ks0
  uint32_t x1 = lo + ks1;
#define TFR(r) { x0 += x1; x1 = rotl32(x1, (r)); x1 ^= x0; }
  TFR(13) TFR(15) TFR(26) TFR(6)
  x0 += ks1; x1 += ks2 + 1u;
  TFR(17) TFR(29) TFR(16) TFR(24)
  x0 += ks2; x1 += ks0 + 2u;
  TFR(13) TFR(15) TFR(26) TFR(6)
  x0 += ks0; x1 += ks1 + 3u;
  TFR(17) TFR(29) TFR(16) TFR(24)
  x0 += ks1; x1 += ks2 + 4u;
  TFR(13) TFR(15) TFR(26) TFR(6)
  x0 += ks2; x1 += ks0 + 5u;
#undef TFR
  return x0 ^ x1;
}

// EXACT float sequence of the verified round-2 pass (monotone in u23).
__device__ __forceinline__ float g_of_u23(uint32_t u23) {
  float u0 = (float)u23 * 0x1p-23f;
  float u  = fmaxf(u0 + 1.17549435e-38f, 1.17549435e-38f);
  float nl = -logf(u);
  return -logf(nl);
}

// Conservative packed threshold: any code with exact g < (gthr - margins) is pruned.
__device__ __forceinline__ uint32_t thr_from_gthr(float gthr) {
  float u_t = expf(-expf(-gthr));
  int B = (int)floorf(u_t * 8388608.0f) - 16;
  if (B < 0) B = 0;
  return ((uint32_t)B) << 9;
}

// ---------------- kernel 0: row-normalize codebook ----------------
__global__ void k_norm(const float* __restrict__ w, float* __restrict__ embn) {
  int k = blockIdx.x;   // 512 rows
  int d = threadIdx.x;  // 64 lanes
  float v = w[(k << 6) + d];
  float s = v * v;
#pragma unroll
  for (int off = 1; off < 64; off <<= 1) s += __shfl_xor(s, off);
  embn[(k << 6) + d] = v / sqrtf(s);
}

// ---------------- kernel 1: register-resident gumbel argmax ----------------
// block = 256 threads = 16 tokens x 16 lanes; each lane owns 32 consecutive k.
__global__ __launch_bounds__(256, 4) void k_top(
    const float* __restrict__ z_e, const float* __restrict__ embn,
    const float* __restrict__ kappa_p, int* __restrict__ idx_ws,
    float* __restrict__ partials, float* __restrict__ out_idx) {
  __shared__ float zs[16 * ZS_STRIDE];   // 4352 B
  __shared__ float redbuf[16];

  const float kappa = kappa_p[0];
  const int tid = threadIdx.x;
  const int tokloc = tid >> 4;          // 0..15
  const int g = tid & 15;               // lane within token group
  const int t = blockIdx.x * 16 + tokloc;

  // block geometry: 16 consecutive tokens share (b,h); w = w0..w0+15
  const int t0 = blockIdx.x * 16;
  const int b = t0 >> 12, h = (t0 >> 6) & 63, w0 = t0 & 63;
  const float* zb = z_e + (b << 18) + (h << 6) + w0;

  // stage z: zs[wloc][d]  (coalesced 16-float segments per (i,dgroup))
  {
    int wloc = tid & 15;
    int dbase = tid >> 4;               // 0..15
#pragma unroll
    for (int i = 0; i < 4; ++i) {
      int d = dbase + (i << 4);
      zs[wloc * ZS_STRIDE + d] = zb[(d << 12) + wloc];
    }
  }
  __syncthreads();

  const float* zrow = zs + tokloc * ZS_STRIDE;
  const uint32_t base = ((uint32_t)t << 9) + (uint32_t)(g << 5);

  // ---- phase 1: 32 threefry, ALL packed values kept in registers ----
  uint32_t p[32];
  uint32_t rm = 0;
#pragma unroll
  for (int j = 0; j < 32; ++j) {
    uint32_t bits = tf_bits_xor(base + (uint32_t)j);
    uint32_t pk = (bits & 0xFFFFFE00u) | (uint32_t)((g << 5) + j);
    p[j] = pk;
    rm = rm > pk ? rm : pk;
  }
  // token-wide bits-max via 16-lane butterfly
#pragma unroll
  for (int off = 1; off < 16; off <<= 1) {
    uint32_t o = __shfl_xor(rm, off, 16);
    rm = rm > o ? rm : o;
  }

  // ---- cooperative eval of v(rmax) -> conservative threshold B2 ----
  uint32_t B2;
  {
    int k = (int)(rm & 511u);
    const float4 e4 = *reinterpret_cast<const float4*>(embn + (k << 6) + (g << 2));
    const float4 z4 = *reinterpret_cast<const float4*>(zrow + (g << 2));
    float part;
    part = fmaf(z4.x, e4.x, 0.0f);
    part = fmaf(z4.y, e4.y, part);
    part = fmaf(z4.z, e4.z, part);
    part = fmaf(z4.w, e4.w, part);
#pragma unroll
    for (int off = 1; off < 16; off <<= 1) part += __shfl_xor(part, off, 16);
    float gm = g_of_u23(rm >> 9);
    float Lb = fmaf(kappa, part, gm);   // ~v(rmax) up to dot-order rounding (<1e-5)
    // winner w: v_w >= v(rmax) >= Lb - 1e-5  =>  g_w >= Lb - kappa*s_w - eps
    B2 = thr_from_gthr(Lb - 1.0001f * kappa - 0.001f);
  }

  // ---- phase 2: static register scan; rare exact evals (round-2 arithmetic) ----
  float best = -INFINITY, bsim = 0.0f;
  int bk = 0;
#pragma unroll
  for (int j = 0; j < 32; ++j) {
    if (p[j] >= B2) {
      int k = (int)(p[j] & 511u);
      const float* e = embn + (k << 6);
      float s0 = 0.f, s1 = 0.f, s2 = 0.f, s3 = 0.f;
#pragma unroll
      for (int d = 0; d < 64; d += 4) {
        float4 e4 = *reinterpret_cast<const float4*>(e + d);
        s0 = fmaf(zrow[d + 0], e4.x, s0);
        s1 = fmaf(zrow[d + 1], e4.y, s1);
        s2 = fmaf(zrow[d + 2], e4.z, s2);
        s3 = fmaf(zrow[d + 3], e4.w, s3);
      }
      float s = (s0 + s1) + (s2 + s3);
      float gg = g_of_u23(p[j] >> 9);
      float v = fmaf(kappa, s, gg);
      if (v > best) { best = v; bk = k; bsim = s; }  // ascending k per lane
    }
  }

  // ---- token-wide lexicographic (max v, min k) == first-occurrence argmax ----
#pragma unroll
  for (int off = 1; off < 16; off <<= 1) {
    float vv = __shfl_xor(best, off, 16);
    float ss = __shfl_xor(bsim, off, 16);
    int   kk = __shfl_xor(bk,   off, 16);
    if (vv > best || (vv == best && kk < bk)) { best = vv; bk = kk; bsim = ss; }
  }

  if (g == 0) {
    idx_ws[t] = bk;
    out_idx[t] = (float)bk;
    redbuf[tokloc] = kappa * (1.0f - bsim);
  }
  __syncthreads();
  if (tid == 0) {
    float s = 0.f;
#pragma unroll
    for (int i = 0; i < 16; ++i) s += redbuf[i];
    partials[blockIdx.x] = s;
  }
}

// ---------------- kernel 2: reduce 8192 partials -> reg ----------------
__global__ __launch_bounds__(256) void k_reg(const float* __restrict__ partials,
                                             float* __restrict__ out_reg) {
  int tid = threadIdx.x;   // 256
  float s = 0.f;
#pragma unroll
  for (int j = 0; j < 32; ++j) s += partials[(j << 8) + tid];
#pragma unroll
  for (int off = 32; off; off >>= 1) s += __shfl_down(s, off);
  __shared__ float l[4];
  int lane = tid & 63, wid = tid >> 6;
  if (lane == 0) l[wid] = s;
  __syncthreads();
  if (tid == 0) out_reg[0] = ((l[0] + l[1]) + (l[2] + l[3])) * (1.0f / 131072.0f);
}

// ---------------- kernel 3: gather z_q via LDS transpose ----------------
__global__ __launch_bounds__(256) void k_gather(
    const float* __restrict__ embn, const int* __restrict__ idx_ws,
    float* __restrict__ out_zq) {
  __shared__ float erow[64 * ECSTRIDE];
  __shared__ int sidx[64];
  int blk = blockIdx.x;            // 2048 = 32*64
  int b = blk >> 6, h = blk & 63;
  int tid = threadIdx.x;
  int lane = tid & 63, wid = tid >> 6;

  if (tid < 64) sidx[tid] = idx_ws[(b << 12) + (h << 6) + tid];
  __syncthreads();
  for (int r = wid; r < 64; r += 4)            // wave per row
    erow[r * ECSTRIDE + lane] = embn[(sidx[r] << 6) + lane];
  __syncthreads();

  int w = tid & 63;
  int d0 = tid >> 6;               // 0..3
  float* outp = out_zq + (b << 18) + (h << 6) + w;
#pragma unroll
  for (int i = 0; i < 16; ++i) {
    int d = (i << 2) + d0;
    outp[d << 12] = erow[w * ECSTRIDE + d];
  }
}

extern "C" void kernel_launch(void* const* d_in, const int* in_sizes, int n_in,
                              void* d_out, int out_size, void* d_ws, size_t ws_size,
                              hipStream_t stream) {
  const float* z_e    = (const float*)d_in[0];
  const float* emb_w  = (const float*)d_in[1];
  const float* kappa  = (const float*)d_in[2];

  float* embn     = (float*)d_ws;                              // 32768 f32
  int*   idx_ws   = (int*)((char*)d_ws + 131072);              // 131072 i32
  float* partials = (float*)((char*)d_ws + 131072 + 524288);   // 8192 f32

  float* out     = (float*)d_out;
  float* out_zq  = out;                    // [8388608]
  float* out_reg = out + ZQ_ELEMS;         // [1]
  float* out_idx = out + ZQ_ELEMS + 1;     // [131072]

  k_norm  <<<K_CODES, 64, 0, stream>>>(emb_w, embn);
  k_top   <<<N_TOK / 16, 256, 0, stream>>>(z_e, embn, kappa, idx_ws, partials, out_idx);
  k_reg   <<<1, 256, 0, stream>>>(partials, out_reg);
  k_gather<<<2048, 256, 0, stream>>>(embn, idx_ws, out_zq);
}

// Round 6
// 184.663 us; speedup vs baseline: 2.0051x; 1.4277x over previous
//
#include <hip/hip_runtime.h>
#include <stdint.h>

// B=32, D=64, H=64, W=64, K=512; N = B*H*W = 131072 tokens.
#define K_CODES 512
#define N_TOK   131072
#define ZQ_ELEMS 8388608   // 32*64*64*64
#define ZS_STRIDE 68       // floats: %4==0, %32==4 -> 2-way banks (free)
#define ECSTRIDE 65        // k_gather LDS stride

__device__ __forceinline__ uint32_t rotl32(uint32_t x, int d) {
  return (x << d) | (x >> (32 - d));
}

// JAX threefry2x32, key=(0,42), partitionable path: bits = out0^out1, counter=(0,lo).
__device__ __forceinline__ uint32_t tf_bits_xor(uint32_t lo) {
  const uint32_t ks0 = 0u, ks1 = 42u, ks2 = 0x1BD11BDAu ^ 0u ^ 42u;
  uint32_t x0 = 0u;        // hi(=0) + ks0
  uint32_t x1 = lo + ks1;
#define TFR(r) { x0 += x1; x1 = rotl32(x1, (r)); x1 ^= x0; }
  TFR(13) TFR(15) TFR(26) TFR(6)
  x0 += ks1; x1 += ks2 + 1u;
  TFR(17) TFR(29) TFR(16) TFR(24)
  x0 += ks2; x1 += ks0 + 2u;
  TFR(13) TFR(15) TFR(26) TFR(6)
  x0 += ks0; x1 += ks1 + 3u;
  TFR(17) TFR(29) TFR(16) TFR(24)
  x0 += ks1; x1 += ks2 + 4u;
  TFR(13) TFR(15) TFR(26) TFR(6)
  x0 += ks2; x1 += ks0 + 5u;
#undef TFR
  return x0 ^ x1;
}

// EXACT float sequence of the verified round-2 pass (monotone in u23).
__device__ __forceinline__ float g_of_u23(uint32_t u23) {
  float u0 = (float)u23 * 0x1p-23f;
  float u  = fmaxf(u0 + 1.17549435e-38f, 1.17549435e-38f);
  float nl = -logf(u);
  return -logf(nl);
}

// Conservative packed threshold: any code with exact g < (gthr - margins) is pruned.
__device__ __forceinline__ uint32_t thr_from_gthr(float gthr) {
  float u_t = expf(-expf(-gthr));
  int B = (int)floorf(u_t * 8388608.0f) - 16;
  if (B < 0) B = 0;
  return ((uint32_t)B) << 9;
}

// ---------------- kernel 0: row-normalize codebook ----------------
__global__ void k_norm(const float* __restrict__ w, float* __restrict__ embn) {
  int k = blockIdx.x;   // 512 rows
  int d = threadIdx.x;  // 64 lanes
  float v = w[(k << 6) + d];
  float s = v * v;
#pragma unroll
  for (int off = 1; off < 64; off <<= 1) s += __shfl_xor(s, off);
  embn[(k << 6) + d] = v / sqrtf(s);
}

// ---------------- kernel 1: wave-per-token cooperative gumbel argmax --------
// block = 1024 threads = 16 waves = 16 tokens (sharing (b,h), w = w0..w0+15).
// lane = channel d; each lane owns 8 consecutive k in registers.
__global__ __launch_bounds__(1024, 8) void k_top(
    const float* __restrict__ z_e, const float* __restrict__ embn,
    const float* __restrict__ kappa_p, int* __restrict__ idx_ws,
    float* __restrict__ partials, float* __restrict__ out_idx) {
  __shared__ float zs[16 * ZS_STRIDE];   // 4352 B
  __shared__ float redbuf[16];

  const float kappa = kappa_p[0];
  const int tid = threadIdx.x;
  const int wv = tid >> 6;              // token-local 0..15
  const int lane = tid & 63;            // channel d
  const int t0 = blockIdx.x * 16;
  const int t = t0 + wv;
  const int b = t0 >> 12, h = (t0 >> 6) & 63, w0 = t0 & 63;
  const float* zb = z_e + (b << 18) + (h << 6) + w0;

  // stage z for the 16 tokens: coalesced 16-float segments (round-5 pattern)
  if (tid < 256) {
    int wloc = tid & 15;
    int dbase = tid >> 4;               // 0..15
#pragma unroll
    for (int i = 0; i < 4; ++i) {
      int d = dbase + (i << 4);
      zs[wloc * ZS_STRIDE + d] = zb[(d << 12) + wloc];
    }
  }
  __syncthreads();
  const float zv = zs[wv * ZS_STRIDE + lane];   // z[t][d=lane]

  // ---- phase 1: 8 threefry per lane, all packed values in registers ----
  const uint32_t base = ((uint32_t)t << 9) + (uint32_t)(lane << 3);
  uint32_t p[8];
  uint32_t rm = 0;
#pragma unroll
  for (int j = 0; j < 8; ++j) {
    uint32_t bits = tf_bits_xor(base + (uint32_t)j);
    uint32_t pk = (bits & 0xFFFFFE00u) | (uint32_t)((lane << 3) + j);
    p[j] = pk;
    rm = rm > pk ? rm : pk;
  }
  // wave-wide bits-max
#pragma unroll
  for (int off = 1; off < 64; off <<= 1) {
    uint32_t o = __shfl_xor(rm, off);
    rm = rm > o ? rm : o;
  }

  // ---- cooperative eval of v(rmax) -> conservative threshold B2 ----
  uint32_t B2;
  {
    int k = (int)(rm & 511u);
    float e = embn[(k << 6) + lane];          // coalesced 256 B, L2-hot
    float pr = zv * e;
#pragma unroll
    for (int off = 1; off < 64; off <<= 1) pr += __shfl_xor(pr, off);
    float gm = g_of_u23(rm >> 9);
    float vrm = fmaf(kappa, pr, gm);
    // winner w: v_w >= v(rmax) => g_w >= vrm - kappa*s_w - slop
    B2 = thr_from_gthr(vrm - 1.0001f * kappa - 0.001f);
  }

  // ---- phase 2: ballot-enumerated cooperative evals (exact, no caps) ----
  float best = -INFINITY, bsim = 0.0f;
  int bk = 0;
#pragma unroll
  for (int j = 0; j < 8; ++j) {               // static j -> p[j] stays in VGPR
    unsigned long long m = __ballot(p[j] >= B2);
    while (m) {
      int L = __ffsll(m) - 1;
      m &= m - 1;
      uint32_t pk = __shfl(p[j], L);          // broadcast lane L's candidate
      int k = (int)(pk & 511u);
      float e = embn[(k << 6) + lane];
      float pr = zv * e;
#pragma unroll
      for (int off = 1; off < 64; off <<= 1) pr += __shfl_xor(pr, off);
      float gg = g_of_u23(pk >> 9);
      float v = fmaf(kappa, pr, gg);
      // lexicographic (max v, min k) == first-occurrence argmax; identical on
      // all lanes, so every lane ends holding the winner.
      if (v > best || (v == best && k < bk)) { best = v; bk = k; bsim = pr; }
    }
  }

  if (lane == 0) {
    idx_ws[t] = bk;
    out_idx[t] = (float)bk;
    redbuf[wv] = kappa * (1.0f - bsim);
  }
  __syncthreads();
  if (tid == 0) {
    float s = 0.f;
#pragma unroll
    for (int i = 0; i < 16; ++i) s += redbuf[i];
    partials[blockIdx.x] = s;
  }
}

// ---------------- kernel 2: reduce 8192 partials -> reg ----------------
__global__ __launch_bounds__(256) void k_reg(const float* __restrict__ partials,
                                             float* __restrict__ out_reg) {
  int tid = threadIdx.x;   // 256
  float s = 0.f;
#pragma unroll
  for (int j = 0; j < 32; ++j) s += partials[(j << 8) + tid];
#pragma unroll
  for (int off = 32; off; off >>= 1) s += __shfl_down(s, off);
  __shared__ float l[4];
  int lane = tid & 63, wid = tid >> 6;
  if (lane == 0) l[wid] = s;
  __syncthreads();
  if (tid == 0) out_reg[0] = ((l[0] + l[1]) + (l[2] + l[3])) * (1.0f / 131072.0f);
}

// ---------------- kernel 3: gather z_q via LDS transpose ----------------
__global__ __launch_bounds__(256) void k_gather(
    const float* __restrict__ embn, const int* __restrict__ idx_ws,
    float* __restrict__ out_zq) {
  __shared__ float erow[64 * ECSTRIDE];
  __shared__ int sidx[64];
  int blk = blockIdx.x;            // 2048 = 32*64
  int b = blk >> 6, h = blk & 63;
  int tid = threadIdx.x;
  int lane = tid & 63, wid = tid >> 6;

  if (tid < 64) sidx[tid] = idx_ws[(b << 12) + (h << 6) + tid];
  __syncthreads();
  for (int r = wid; r < 64; r += 4)            // wave per row
    erow[r * ECSTRIDE + lane] = embn[(sidx[r] << 6) + lane];
  __syncthreads();

  int w = tid & 63;
  int d0 = tid >> 6;               // 0..3
  float* outp = out_zq + (b << 18) + (h << 6) + w;
#pragma unroll
  for (int i = 0; i < 16; ++i) {
    int d = (i << 2) + d0;
    outp[d << 12] = erow[w * ECSTRIDE + d];
  }
}

extern "C" void kernel_launch(void* const* d_in, const int* in_sizes, int n_in,
                              void* d_out, int out_size, void* d_ws, size_t ws_size,
                              hipStream_t stream) {
  const float* z_e    = (const float*)d_in[0];
  const float* emb_w  = (const float*)d_in[1];
  const float* kappa  = (const float*)d_in[2];

  float* embn     = (float*)d_ws;                              // 32768 f32
  int*   idx_ws   = (int*)((char*)d_ws + 131072);              // 131072 i32
  float* partials = (float*)((char*)d_ws + 131072 + 524288);   // 8192 f32

  float* out     = (float*)d_out;
  float* out_zq  = out;                    // [8388608]
  float* out_reg = out + ZQ_ELEMS;         // [1]
  float* out_idx = out + ZQ_ELEMS + 1;     // [131072]

  k_norm  <<<K_CODES, 64, 0, stream>>>(emb_w, embn);
  k_top   <<<N_TOK / 16, 1024, 0, stream>>>(z_e, embn, kappa, idx_ws, partials, out_idx);
  k_reg   <<<1, 256, 0, stream>>>(partials, out_reg);
  k_gather<<<2048, 256, 0, stream>>>(embn, idx_ws, out_zq);
}

// Round 7
// 177.493 us; speedup vs baseline: 2.0861x; 1.0404x over previous
//
#include <hip/hip_runtime.h>
#include <stdint.h>

// B=32, D=64, H=64, W=64, K=512; N = B*H*W = 131072 tokens.
#define K_CODES 512
#define N_TOK   131072
#define ZQ_ELEMS 8388608   // 32*64*64*64
#define ZS_STRIDE 68       // floats: %4==0, %32==4 -> 2-way banks (free)
#define ECSTRIDE 65        // k_gather LDS stride

__device__ __forceinline__ uint32_t rotl32(uint32_t x, int d) {
  return (x << d) | (x >> (32 - d));
}

// JAX threefry2x32, key=(0,42), partitionable path: bits = out0^out1, counter=(0,lo).
__device__ __forceinline__ uint32_t tf_bits_xor(uint32_t lo) {
  const uint32_t ks0 = 0u, ks1 = 42u, ks2 = 0x1BD11BDAu ^ 0u ^ 42u;
  uint32_t x0 = 0u;        // hi(=0) + ks0
  uint32_t x1 = lo + ks1;
#define TFR(r) { x0 += x1; x1 = rotl32(x1, (r)); x1 ^= x0; }
  TFR(13) TFR(15) TFR(26) TFR(6)
  x0 += ks1; x1 += ks2 + 1u;
  TFR(17) TFR(29) TFR(16) TFR(24)
  x0 += ks2; x1 += ks0 + 2u;
  TFR(13) TFR(15) TFR(26) TFR(6)
  x0 += ks0; x1 += ks1 + 3u;
  TFR(17) TFR(29) TFR(16) TFR(24)
  x0 += ks1; x1 += ks2 + 4u;
  TFR(13) TFR(15) TFR(26) TFR(6)
  x0 += ks2; x1 += ks0 + 5u;
#undef TFR
  return x0 ^ x1;
}

// EXACT float sequence of the verified round-2 pass (monotone in u23).
// Used ONLY where the value feeds the argmax comparison (must be bit-exact).
__device__ __forceinline__ float g_of_u23(uint32_t u23) {
  float u0 = (float)u23 * 0x1p-23f;
  float u  = fmaxf(u0 + 1.17549435e-38f, 1.17549435e-38f);
  float nl = -logf(u);
  return -logf(nl);
}

// FAST conservative packed threshold (pruning only, never feeds outputs).
// __expf rel err ~1e-6 -> u_t off by <= ~25 u23-units; slack of 64 units keeps
// it strictly conservative (cut too low = extra work, never wrong).
__device__ __forceinline__ uint32_t thr_fast(float gthr) {
  float u_t = __expf(-__expf(-gthr));
  int B = (int)floorf(u_t * 8388608.0f) - 64;
  if (B < 0) B = 0;
  return ((uint32_t)B) << 9;
}

// ---------------- kernel 0: row-normalize codebook ----------------
__global__ void k_norm(const float* __restrict__ w, float* __restrict__ embn) {
  int k = blockIdx.x;   // 512 rows
  int d = threadIdx.x;  // 64 lanes
  float v = w[(k << 6) + d];
  float s = v * v;
#pragma unroll
  for (int off = 1; off < 64; off <<= 1) s += __shfl_xor(s, off);
  embn[(k << 6) + d] = v / sqrtf(s);
}

// ---------------- kernel 1: wave-per-token cooperative gumbel argmax --------
// block = 1024 threads = 16 waves = 16 tokens (sharing (b,h), w = w0..w0+15).
// lane = channel d; each lane owns 8 consecutive k in registers.
__global__ __launch_bounds__(1024, 8) void k_top(
    const float* __restrict__ z_e, const float* __restrict__ embn,
    const float* __restrict__ kappa_p, int* __restrict__ idx_ws,
    float* __restrict__ partials, float* __restrict__ out_idx) {
  __shared__ float zs[16 * ZS_STRIDE];   // 4352 B
  __shared__ float redbuf[16];

  const float kappa = kappa_p[0];
  const int tid = threadIdx.x;
  const int wv = tid >> 6;              // token-local 0..15
  const int lane = tid & 63;            // channel d
  const int t0 = blockIdx.x * 16;
  const int t = t0 + wv;
  const int b = t0 >> 12, h = (t0 >> 6) & 63, w0 = t0 & 63;
  const float* zb = z_e + (b << 18) + (h << 6) + w0;

  // stage z for the 16 tokens: coalesced 16-float segments
  if (tid < 256) {
    int wloc = tid & 15;
    int dbase = tid >> 4;               // 0..15
#pragma unroll
    for (int i = 0; i < 4; ++i) {
      int d = dbase + (i << 4);
      zs[wloc * ZS_STRIDE + d] = zb[(d << 12) + wloc];
    }
  }
  __syncthreads();
  const float zv = zs[wv * ZS_STRIDE + lane];   // z[t][d=lane]

  // ---- phase 1: 8 threefry per lane, all packed values in registers ----
  const uint32_t base = ((uint32_t)t << 9) + (uint32_t)(lane << 3);
  uint32_t p[8];
  uint32_t rm = 0;
#pragma unroll
  for (int j = 0; j < 8; ++j) {
    uint32_t bits = tf_bits_xor(base + (uint32_t)j);
    uint32_t pk = (bits & 0xFFFFFE00u) | (uint32_t)((lane << 3) + j);
    p[j] = pk;
    rm = rm > pk ? rm : pk;
  }
  // wave-wide bits-max (all lanes end with identical rm)
#pragma unroll
  for (int off = 1; off < 64; off <<= 1) {
    uint32_t o = __shfl_xor(rm, off);
    rm = rm > o ? rm : o;
  }

  // ---- exact eval of v(rmax): seeds the argmax state AND the cut ----
  float best, bsim;
  int bk;
  {
    int k = (int)(rm & 511u);
    float e = embn[(k << 6) + lane];          // coalesced 256 B, L2-hot
    float pr = zv * e;
#pragma unroll
    for (int off = 1; off < 64; off <<= 1) pr += __shfl_xor(pr, off);
    float gm = g_of_u23(rm >> 9);             // precise (feeds comparisons)
    best = fmaf(kappa, pr, gm);
    bsim = pr;
    bk = k;
  }
  uint32_t cut = thr_fast(best - 1.0001f * kappa - 0.001f);

  // ---- phase 2: ballot-enumerated evals with tightening integer cut ----
#pragma unroll
  for (int j = 0; j < 8; ++j) {               // static j -> p[j] stays in VGPR
    unsigned long long m = __ballot(p[j] >= cut);
    while (m) {
      int L = __ffsll(m) - 1;
      m &= m - 1;
      uint32_t pk = __shfl(p[j], L);          // broadcast lane L's candidate
      if (pk == rm) continue;                 // already evaluated (uniform)
      if (pk < cut) continue;                 // cut tightened since ballot
      int k = (int)(pk & 511u);
      float e = embn[(k << 6) + lane];
      float pr = zv * e;
#pragma unroll
      for (int off = 1; off < 64; off <<= 1) pr += __shfl_xor(pr, off);
      float gg = g_of_u23(pk >> 9);           // precise (feeds comparisons)
      float v = fmaf(kappa, pr, gg);
      // lexicographic (max v, min k) == first-occurrence argmax; identical on
      // all lanes, so every lane ends holding the winner.
      if (v > best || (v == best && k < bk)) {
        best = v; bk = k; bsim = pr;
        cut = thr_fast(best - 1.0001f * kappa - 0.001f);
      }
    }
  }

  if (lane == 0) {
    idx_ws[t] = bk;
    out_idx[t] = (float)bk;
    redbuf[wv] = kappa * (1.0f - bsim);
  }
  __syncthreads();
  if (tid == 0) {
    float s = 0.f;
#pragma unroll
    for (int i = 0; i < 16; ++i) s += redbuf[i];
    partials[blockIdx.x] = s;
  }
}

// ---------------- kernel 2: reduce 8192 partials -> reg ----------------
__global__ __launch_bounds__(256) void k_reg(const float* __restrict__ partials,
                                             float* __restrict__ out_reg) {
  int tid = threadIdx.x;   // 256
  float s = 0.f;
#pragma unroll
  for (int j = 0; j < 32; ++j) s += partials[(j << 8) + tid];
#pragma unroll
  for (int off = 32; off; off >>= 1) s += __shfl_down(s, off);
  __shared__ float l[4];
  int lane = tid & 63, wid = tid >> 6;
  if (lane == 0) l[wid] = s;
  __syncthreads();
  if (tid == 0) out_reg[0] = ((l[0] + l[1]) + (l[2] + l[3])) * (1.0f / 131072.0f);
}

// ---------------- kernel 3: gather z_q via LDS transpose ----------------
__global__ __launch_bounds__(256) void k_gather(
    const float* __restrict__ embn, const int* __restrict__ idx_ws,
    float* __restrict__ out_zq) {
  __shared__ float erow[64 * ECSTRIDE];
  __shared__ int sidx[64];
  int blk = blockIdx.x;            // 2048 = 32*64
  int b = blk >> 6, h = blk & 63;
  int tid = threadIdx.x;
  int lane = tid & 63, wid = tid >> 6;

  if (tid < 64) sidx[tid] = idx_ws[(b << 12) + (h << 6) + tid];
  __syncthreads();
  for (int r = wid; r < 64; r += 4)            // wave per row
    erow[r * ECSTRIDE + lane] = embn[(sidx[r] << 6) + lane];
  __syncthreads();

  int w = tid & 63;
  int d0 = tid >> 6;               // 0..3
  float* outp = out_zq + (b << 18) + (h << 6) + w;
#pragma unroll
  for (int i = 0; i < 16; ++i) {
    int d = (i << 2) + d0;
    outp[d << 12] = erow[w * ECSTRIDE + d];
  }
}

extern "C" void kernel_launch(void* const* d_in, const int* in_sizes, int n_in,
                              void* d_out, int out_size, void* d_ws, size_t ws_size,
                              hipStream_t stream) {
  const float* z_e    = (const float*)d_in[0];
  const float* emb_w  = (const float*)d_in[1];
  const float* kappa  = (const float*)d_in[2];

  float* embn     = (float*)d_ws;                              // 32768 f32
  int*   idx_ws   = (int*)((char*)d_ws + 131072);              // 131072 i32
  float* partials = (float*)((char*)d_ws + 131072 + 524288);   // 8192 f32

  float* out     = (float*)d_out;
  float* out_zq  = out;                    // [8388608]
  float* out_reg = out + ZQ_ELEMS;         // [1]
  float* out_idx = out + ZQ_ELEMS + 1;     // [131072]

  k_norm  <<<K_CODES, 64, 0, stream>>>(emb_w, embn);
  k_top   <<<N_TOK / 16, 1024, 0, stream>>>(z_e, embn, kappa, idx_ws, partials, out_idx);
  k_reg   <<<1, 256, 0, stream>>>(partials, out_reg);
  k_gather<<<2048, 256, 0, stream>>>(embn, idx_ws, out_zq);
}